// Round 15
// baseline (88.049 us; speedup 1.0000x reference)
//
#include <hip/hip_runtime.h>
#include <cstddef>

#define QK_SCALE 0.17677669529663687f   // 1/sqrt(32)

#define FMA4(acc, sc, c) \
    acc.x = fmaf(sc, c.x, acc.x); acc.y = fmaf(sc, c.y, acc.y); \
    acc.z = fmaf(sc, c.z, acc.z); acc.w = fmaf(sc, c.w, acc.w);
#define SCL4(dst, s, v) \
    dst.x = s*v.x; dst.y = s*v.y; dst.z = s*v.z; dst.w = s*v.w;

// 16-lane split-ownership tree reduce (8 head-dots -> 1 per lane)
__device__ __forceinline__ float hred16(float4 dA, float4 dB, int sg) {
    float4 give = (sg & 1) ? dA : dB;
    float4 keep = (sg & 1) ? dB : dA;
    keep.x += __shfl_xor(give.x, 1); keep.y += __shfl_xor(give.y, 1);
    keep.z += __shfl_xor(give.z, 1); keep.w += __shfl_xor(give.w, 1);
    float g0 = (sg & 2) ? keep.x : keep.z;
    float g1 = (sg & 2) ? keep.y : keep.w;
    float e0 = (sg & 2) ? keep.z : keep.x;
    float e1 = (sg & 2) ? keep.w : keep.y;
    e0 += __shfl_xor(g0, 2); e1 += __shfl_xor(g1, 2);
    float g2 = (sg & 4) ? e0 : e1;
    float d  = (sg & 4) ? e1 : e0;
    d += __shfl_xor(g2, 4);
    d += __shfl_xor(d, 8);
    return d;
}

// ===== KA (512 thr, VGPR cap 128): [0,256) proj + out-init ; [256,1280) bias-LN @Wb =====
__global__ __launch_bounds__(512, 2) void kA(
    const float* __restrict__ x, const int* __restrict__ mask,
    const float* __restrict__ lng, const float* __restrict__ lnb,
    const float* __restrict__ Wq, const float* __restrict__ Wk,
    const float* __restrict__ Wv, const float* __restrict__ Wg,
    const float* __restrict__ bgv,
    const float* __restrict__ lnbg, const float* __restrict__ lnbb,
    const float* __restrict__ Wb, const float* __restrict__ bias,
    const float* __restrict__ bo,
    float* __restrict__ qg, float* __restrict__ ktg,
    float* __restrict__ vg, float* __restrict__ gateg,
    float* __restrict__ bh, float* __restrict__ out)
{
    __shared__ float xn_s[4][256];
    __shared__ int kl_s[512];
    __shared__ int cnt_s[8];
    const int tid = threadIdx.x;
    const int w = tid >> 6, lane = tid & 63;

    if (blockIdx.x >= 256) {
        // -------- bias path: block = (b, q); 8 waves x 4 row-groups = 32 rows/pass --------
        const int bid2 = blockIdx.x - 256;
        const int b = bid2 >> 9;
        const int q = bid2 & 511;
        if (mask[(b << 9) + q] == 0) return;          // block-uniform exit

        // in-block compaction: 512 threads cover all k directly
        const int mreg = (mask[(b << 9) + tid] != 0);
        unsigned long long bal = __ballot(mreg);
        if (lane == 0) cnt_s[w] = __popcll(bal);
        __syncthreads();
        int nk = 0;
        #pragma unroll
        for (int j = 0; j < 8; ++j) nk += cnt_s[j];
        int base = 0;
        #pragma unroll
        for (int j = 0; j < 8; ++j) base += (j < w) ? cnt_s[j] : 0;
        if (mreg)
            kl_s[base + __popcll(bal & ((1ull << lane) - 1ull))] = tid;

        // per-lane coefficients + S1/S2 from Wb/lnbg/lnbb
        const int rq = lane >> 4;
        const int sg = lane & 15;
        const int h  = ((sg & 1) << 2) + (sg & 2) + ((sg >> 2) & 1);
        float4 cA0[4], cB0[4], cA1[4], cB1[4];
        float4 s1a = {0,0,0,0}, s1b = {0,0,0,0}, s2a = {0,0,0,0}, s2b = {0,0,0,0};
        #pragma unroll
        for (int j = 0; j < 4; ++j) {
            int c0 = 4*sg + j, c1 = 64 + 4*sg + j;
            float4 wa = *reinterpret_cast<const float4*>(Wb + c0*8);
            float4 wb = *reinterpret_cast<const float4*>(Wb + c0*8 + 4);
            float ga = lnbg[c0], bbv = lnbb[c0];
            SCL4(cA0[j], ga, wa); SCL4(cB0[j], ga, wb);
            FMA4(s1a, ga, wa); FMA4(s1b, ga, wb);
            FMA4(s2a, bbv, wa); FMA4(s2b, bbv, wb);
            float4 wa1 = *reinterpret_cast<const float4*>(Wb + c1*8);
            float4 wb1 = *reinterpret_cast<const float4*>(Wb + c1*8 + 4);
            float ga1 = lnbg[c1], bbv1 = lnbb[c1];
            SCL4(cA1[j], ga1, wa1); SCL4(cB1[j], ga1, wb1);
            FMA4(s1a, ga1, wa1); FMA4(s1b, ga1, wb1);
            FMA4(s2a, bbv1, wa1); FMA4(s2b, bbv1, wb1);
        }
        const float S1 = hred16(s1a, s1b, sg);
        const float S2 = hred16(s2a, s2b, sg);

        const float4* brow = reinterpret_cast<const float4*>(
            bias + (size_t)((b << 9) + q) * 512 * 128);
        __syncthreads();   // kl_s ready

        const int slot = (w << 2) + rq;               // 0..31
        for (int p = 0; (p << 5) < nk; ++p) {
            const int i = (p << 5) + slot;
            if (i < nk) {
                const int k = kl_s[i];
                const float4* bp = brow + (size_t)k * 32;
                float4 v0 = bp[sg];
                float4 v1 = bp[16 + sg];

                float s  = v0.x+v0.y+v0.z+v0.w + v1.x+v1.y+v1.z+v1.w;
                float ss = v0.x*v0.x; ss = fmaf(v0.y,v0.y, ss); ss = fmaf(v0.z,v0.z, ss);
                ss = fmaf(v0.w,v0.w, ss); ss = fmaf(v1.x,v1.x, ss); ss = fmaf(v1.y,v1.y, ss);
                ss = fmaf(v1.z,v1.z, ss); ss = fmaf(v1.w,v1.w, ss);

                float4 dA = {0.f,0.f,0.f,0.f}, dB = {0.f,0.f,0.f,0.f};
                FMA4(dA, v0.x, cA0[0]); FMA4(dB, v0.x, cB0[0]);
                FMA4(dA, v0.y, cA0[1]); FMA4(dB, v0.y, cB0[1]);
                FMA4(dA, v0.z, cA0[2]); FMA4(dB, v0.z, cB0[2]);
                FMA4(dA, v0.w, cA0[3]); FMA4(dB, v0.w, cB0[3]);
                FMA4(dA, v1.x, cA1[0]); FMA4(dB, v1.x, cB1[0]);
                FMA4(dA, v1.y, cA1[1]); FMA4(dB, v1.y, cB1[1]);
                FMA4(dA, v1.z, cA1[2]); FMA4(dB, v1.z, cB1[2]);
                FMA4(dA, v1.w, cA1[3]); FMA4(dB, v1.w, cB1[3]);

                float dsum = hred16(dA, dB, sg);
                #pragma unroll
                for (int m = 1; m < 16; m <<= 1) {
                    s  += __shfl_xor(s,  m);
                    ss += __shfl_xor(ss, m);
                }
                float mean = s * (1.f/128.f);
                float rstd = rsqrtf(ss*(1.f/128.f) - mean*mean + 1e-5f);
                if (sg < 8)
                    bh[((size_t)((b*8 + h) * 512) + q) * 512 + k] = rstd * (dsum - mean*S1) + S2;
            }
        }
        return;
    }

    // -------- proj path: 4 rows; matrix m on waves {m, m+4} (2 rows each) --------
    const int gr0 = blockIdx.x * 4;

    if (w < 4) {
        const int row = gr0 + w;
        float4 xv = *reinterpret_cast<const float4*>(x + (size_t)row * 256 + lane * 4);
        float s  = xv.x + xv.y + xv.z + xv.w;
        float ss = xv.x*xv.x + xv.y*xv.y + xv.z*xv.z + xv.w*xv.w;
        #pragma unroll
        for (int m = 1; m < 64; m <<= 1) { s += __shfl_xor(s, m); ss += __shfl_xor(ss, m); }
        float mean = s * (1.f/256.f);
        float rstd = rsqrtf(ss*(1.f/256.f) - mean*mean + 1e-5f);
        float4 g4 = *reinterpret_cast<const float4*>(lng + lane*4);
        float4 b4 = *reinterpret_cast<const float4*>(lnb + lane*4);
        float4 xn;
        xn.x = (xv.x-mean)*rstd*g4.x + b4.x;
        xn.y = (xv.y-mean)*rstd*g4.y + b4.y;
        xn.z = (xv.z-mean)*rstd*g4.z + b4.z;
        xn.w = (xv.w-mean)*rstd*g4.w + b4.w;
        *reinterpret_cast<float4*>(&xn_s[w][lane*4]) = xn;
    }
    // out init: bo for unmasked rows, 0 for masked (KB atomically adds head terms)
    #pragma unroll
    for (int i = tid; i < 1024; i += 512) {
        int gr = gr0 + (i >> 8), cc = i & 255;
        out[(size_t)gr * 256 + cc] = (mask[gr] == 0) ? 0.f : bo[cc];
    }
    __syncthreads();

    const int mat = w & 3;
    const int r0p = (w >> 2) << 1;    // rows r0p, r0p+1
    const float* W = (mat == 0) ? Wq : (mat == 1) ? Wk : (mat == 2) ? Wv : Wg;
    const int col = lane << 2;
    float a[2][4];
    #pragma unroll
    for (int r = 0; r < 2; ++r)
        #pragma unroll
        for (int c = 0; c < 4; ++c) a[r][c] = 0.f;

    #pragma unroll 4
    for (int c = 0; c < 256; c += 4) {
        float4 w0 = *reinterpret_cast<const float4*>(W + (size_t)(c+0)*256 + col);
        float4 w1 = *reinterpret_cast<const float4*>(W + (size_t)(c+1)*256 + col);
        float4 w2 = *reinterpret_cast<const float4*>(W + (size_t)(c+2)*256 + col);
        float4 w3 = *reinterpret_cast<const float4*>(W + (size_t)(c+3)*256 + col);
        #pragma unroll
        for (int r = 0; r < 2; ++r) {
            float4 xr = *reinterpret_cast<const float4*>(&xn_s[r0p + r][c]);
            a[r][0] = fmaf(xr.x,w0.x, fmaf(xr.y,w1.x, fmaf(xr.z,w2.x, fmaf(xr.w,w3.x, a[r][0]))));
            a[r][1] = fmaf(xr.x,w0.y, fmaf(xr.y,w1.y, fmaf(xr.z,w2.y, fmaf(xr.w,w3.y, a[r][1]))));
            a[r][2] = fmaf(xr.x,w0.z, fmaf(xr.y,w1.z, fmaf(xr.z,w2.z, fmaf(xr.w,w3.z, a[r][2]))));
            a[r][3] = fmaf(xr.x,w0.w, fmaf(xr.y,w1.w, fmaf(xr.z,w2.w, fmaf(xr.w,w3.w, a[r][3]))));
        }
    }

    if (mat == 0) {
        #pragma unroll
        for (int r = 0; r < 2; ++r) {
            float4 o; o.x=a[r][0]; o.y=a[r][1]; o.z=a[r][2]; o.w=a[r][3];
            *reinterpret_cast<float4*>(qg + (size_t)(gr0+r0p+r)*256 + col) = o;
        }
    } else if (mat == 1) {
        #pragma unroll
        for (int r = 0; r < 2; ++r) {
            int gr = gr0 + r0p + r, gb = gr >> 9, gl = gr & 511;
            #pragma unroll
            for (int jj = 0; jj < 4; ++jj) {
                int c2 = col + jj;
                ktg[((size_t)(gb*8 + (c2>>5))*32 + (c2&31))*512 + gl] = a[r][jj] * QK_SCALE;
            }
        }
    } else if (mat == 2) {
        #pragma unroll
        for (int r = 0; r < 2; ++r) {
            float4 o; o.x=a[r][0]; o.y=a[r][1]; o.z=a[r][2]; o.w=a[r][3];
            *reinterpret_cast<float4*>(vg + (size_t)(gr0+r0p+r)*256 + col) = o;
        }
    } else {
        float4 bg4 = *reinterpret_cast<const float4*>(bgv + col);
        #pragma unroll
        for (int r = 0; r < 2; ++r) {
            float4 o;
            o.x = 1.f/(1.f + __expf(-(a[r][0] + bg4.x)));
            o.y = 1.f/(1.f + __expf(-(a[r][1] + bg4.y)));
            o.z = 1.f/(1.f + __expf(-(a[r][2] + bg4.z)));
            o.w = 1.f/(1.f + __expf(-(a[r][3] + bg4.w)));
            *reinterpret_cast<float4*>(gateg + (size_t)(gr0+r0p+r)*256 + col) = o;
        }
    }
}

// ========= KB: attention per (b,h,32q) + fused Wo epilogue (atomicAdd) — R10 exact =========
__global__ __launch_bounds__(512, 2) void kB(
    const float* __restrict__ qg, const float* __restrict__ ktg,
    const float* __restrict__ vg, const float* __restrict__ gateg,
    const float* __restrict__ bh, const int* __restrict__ mask,
    const float* __restrict__ Wo, float* __restrict__ out)
{
    __shared__ float kv_s[8192];        // K [32][128] | V [128][32]; reused for Wo slice
    __shared__ float q_s[32][32];
    __shared__ float p_s[8][4][128];
    __shared__ float att_s[32][32];

    const int tid = threadIdx.x;
    const int bid = blockIdx.x;
    const int b  = bid >> 7;
    const int h  = (bid >> 4) & 7;
    const int qt = bid & 15;
    const int w = tid >> 6, lane = tid & 63;
    const int ql = lane >> 5, dd2 = lane & 31;
    const int mq = b << 9;
    const int q0 = qt << 5;
    const int qw = q0 + (w << 2);

    {
        int qr = tid >> 4, dd = (tid & 15) << 1;
        float2 v = *reinterpret_cast<const float2*>(
            qg + (size_t)(mq + q0 + qr) * 256 + (h << 5) + dd);
        *reinterpret_cast<float2*>(&q_s[qr][dd]) = v;
    }

    float mrun[4] = {-1e30f, -1e30f, -1e30f, -1e30f};
    float sden[4] = {0.f, 0.f, 0.f, 0.f};
    float a0A=0.f, a0B=0.f, a1A=0.f, a1B=0.f;

    for (int kt2 = 0; kt2 < 4; ++kt2) {
        const int k0 = kt2 << 7;
        __syncthreads();
        {
            int d = tid >> 4, kk = (tid & 15) << 3;
            const float* src = ktg + ((size_t)((b << 3) + h) * 32 + d) * 512 + k0 + kk;
            float4 a4 = *reinterpret_cast<const float4*>(src);
            float4 b4 = *reinterpret_cast<const float4*>(src + 4);
            *reinterpret_cast<float4*>(&kv_s[d * 128 + kk])     = a4;
            *reinterpret_cast<float4*>(&kv_s[d * 128 + kk + 4]) = b4;
            int k = tid >> 2, dd = (tid & 3) << 3;
            const float* vs = vg + (size_t)(mq + k0 + k) * 256 + (h << 5) + dd;
            float4 c4 = *reinterpret_cast<const float4*>(vs);
            float4 e4 = *reinterpret_cast<const float4*>(vs + 4);
            *reinterpret_cast<float4*>(&kv_s[4096 + k * 32 + dd])     = c4;
            *reinterpret_cast<float4*>(&kv_s[4096 + k * 32 + dd + 4]) = e4;
        }
        __syncthreads();

        const int mkA = (mask[mq + k0 + lane] == 0);
        const int mkB = (mask[mq + k0 + 64 + lane] == 0);

        float bhA[4], bhB[4];
        #pragma unroll
        for (int qq = 0; qq < 4; ++qq) {
            const float* r = bh + (((size_t)(b*8 + h) * 512) + qw + qq) * 512 + k0;
            bhA[qq] = r[lane];
            bhB[qq] = r[64 + lane];
        }

        float lA[4] = {0.f,0.f,0.f,0.f}, lB[4] = {0.f,0.f,0.f,0.f};
        #pragma unroll
        for (int d4 = 0; d4 < 32; d4 += 4) {
            float4 q4[4];
            #pragma unroll
            for (int qq = 0; qq < 4; ++qq)
                q4[qq] = *reinterpret_cast<const float4*>(&q_s[(w << 2) + qq][d4]);
            float kv0[4], kv1[4];
            #pragma unroll
            for (int j = 0; j < 4; ++j) {
                kv0[j] = kv_s[(d4 + j) * 128 + lane];
                kv1[j] = kv_s[(d4 + j) * 128 + 64 + lane];
            }
            #pragma unroll
            for (int qq = 0; qq < 4; ++qq) {
                lA[qq] = fmaf(q4[qq].x, kv0[0], lA[qq]);
                lA[qq] = fmaf(q4[qq].y, kv0[1], lA[qq]);
                lA[qq] = fmaf(q4[qq].z, kv0[2], lA[qq]);
                lA[qq] = fmaf(q4[qq].w, kv0[3], lA[qq]);
                lB[qq] = fmaf(q4[qq].x, kv1[0], lB[qq]);
                lB[qq] = fmaf(q4[qq].y, kv1[1], lB[qq]);
                lB[qq] = fmaf(q4[qq].z, kv1[2], lB[qq]);
                lB[qq] = fmaf(q4[qq].w, kv1[3], lB[qq]);
            }
        }

        float corr4[4];
        #pragma unroll
        for (int qq = 0; qq < 4; ++qq) {
            float la = mkA ? -1e30f : (lA[qq] + bhA[qq]);
            float lb = mkB ? -1e30f : (lB[qq] + bhB[qq]);
            float mx = fmaxf(la, lb);
            #pragma unroll
            for (int m = 1; m < 64; m <<= 1) mx = fmaxf(mx, __shfl_xor(mx, m));
            float mnew = fmaxf(mrun[qq], mx);
            float corr = __expf(mrun[qq] - mnew);
            float pa = mkA ? 0.f : __expf(la - mnew);
            float pb = mkB ? 0.f : __expf(lb - mnew);
            float ts = pa + pb;
            #pragma unroll
            for (int m = 1; m < 64; m <<= 1) ts += __shfl_xor(ts, m);
            sden[qq] = sden[qq] * corr + ts;
            mrun[qq] = mnew;
            corr4[qq] = corr;
            p_s[w][qq][lane]      = pa;
            p_s[w][qq][64 + lane] = pb;
        }

        float c0 = ql ? corr4[1] : corr4[0];
        float c1 = ql ? corr4[3] : corr4[2];
        a0A *= c0; a0B *= c0; a1A *= c1; a1B *= c1;
        const float* pr0 = p_s[w][ql];
        const float* pr1 = p_s[w][ql + 2];
        #pragma unroll 4
        for (int k = 0; k < 128; k += 8) {
            float4 p0a = *reinterpret_cast<const float4*>(pr0 + k);
            float4 p0b = *reinterpret_cast<const float4*>(pr0 + k + 4);
            float4 p1a = *reinterpret_cast<const float4*>(pr1 + k);
            float4 p1b = *reinterpret_cast<const float4*>(pr1 + k + 4);
            float v0 = kv_s[4096 + (k+0)*32 + dd2], v1 = kv_s[4096 + (k+1)*32 + dd2];
            float v2 = kv_s[4096 + (k+2)*32 + dd2], v3 = kv_s[4096 + (k+3)*32 + dd2];
            float v4 = kv_s[4096 + (k+4)*32 + dd2], v5 = kv_s[4096 + (k+5)*32 + dd2];
            float v6 = kv_s[4096 + (k+6)*32 + dd2], v7 = kv_s[4096 + (k+7)*32 + dd2];
            a0A = fmaf(p0a.x,v0, fmaf(p0a.y,v1, fmaf(p0a.z,v2, fmaf(p0a.w,v3, a0A))));
            a0B = fmaf(p0b.x,v4, fmaf(p0b.y,v5, fmaf(p0b.z,v6, fmaf(p0b.w,v7, a0B))));
            a1A = fmaf(p1a.x,v0, fmaf(p1a.y,v1, fmaf(p1a.z,v2, fmaf(p1a.w,v3, a1A))));
            a1B = fmaf(p1b.x,v4, fmaf(p1b.y,v5, fmaf(p1b.z,v6, fmaf(p1b.w,v7, a1B))));
        }
    }

    // ---- gated, normalized head output -> LDS (masked q -> 0; guards NaN) ----
    {
        float sd0 = ql ? sden[1] : sden[0];
        float sd1 = ql ? sden[3] : sden[2];
        float g0 = gateg[(size_t)(mq + qw + ql) * 256 + (h << 5) + dd2];
        float g1 = gateg[(size_t)(mq + qw + ql + 2) * 256 + (h << 5) + dd2];
        int iv0 = (mask[mq + qw + ql] == 0);
        int iv1 = (mask[mq + qw + ql + 2] == 0);
        att_s[(w << 2) + ql][dd2]     = iv0 ? 0.f : (a0A + a0B) / sd0 * g0;
        att_s[(w << 2) + ql + 2][dd2] = iv1 ? 0.f : (a1A + a1B) / sd1 * g1;
    }
    __syncthreads();

    // ---- stage Wo head-slice [32][256] into kv_s ----
    {
        const float* wsrc = Wo + (size_t)h * 32 * 256;
        for (int i = tid; i < 2048; i += 512)
            *reinterpret_cast<float4*>(&kv_s[i << 2]) =
                *reinterpret_cast<const float4*>(wsrc + (i << 2));
    }
    __syncthreads();

    // ---- per-head partial of att @ Wo, atomically accumulated into out ----
    {
        const int c2 = tid & 255, qh = tid >> 8;   // qh in {0,1}: rows qh*16..+15
        float acc[16];
        #pragma unroll
        for (int i = 0; i < 16; ++i) acc[i] = 0.f;
        #pragma unroll
        for (int d4 = 0; d4 < 32; d4 += 4) {
            float w0 = kv_s[(d4+0)*256 + c2];
            float w1 = kv_s[(d4+1)*256 + c2];
            float w2 = kv_s[(d4+2)*256 + c2];
            float w3 = kv_s[(d4+3)*256 + c2];
            #pragma unroll
            for (int i = 0; i < 16; ++i) {
                float4 a4 = *reinterpret_cast<const float4*>(&att_s[(qh << 4) + i][d4]);
                acc[i] = fmaf(a4.x,w0, fmaf(a4.y,w1, fmaf(a4.z,w2, fmaf(a4.w,w3, acc[i]))));
            }
        }
        #pragma unroll
        for (int i = 0; i < 16; ++i)
            atomicAdd(out + (size_t)(mq + q0 + (qh << 4) + i) * 256 + c2, acc[i]);
    }
}

extern "C" void kernel_launch(void* const* d_in, const int* in_sizes, int n_in,
                              void* d_out, int out_size, void* d_ws, size_t ws_size,
                              hipStream_t stream)
{
    const float* x    = (const float*)d_in[0];
    const float* bias = (const float*)d_in[1];
    const int*   mask = (const int*)d_in[2];
    const float* lng  = (const float*)d_in[3];
    const float* lnb  = (const float*)d_in[4];
    const float* lnbg = (const float*)d_in[5];
    const float* lnbb = (const float*)d_in[6];
    const float* Wq   = (const float*)d_in[7];
    const float* Wk   = (const float*)d_in[8];
    const float* Wv   = (const float*)d_in[9];
    const float* Wb   = (const float*)d_in[10];
    const float* Wg   = (const float*)d_in[11];
    const float* bgv  = (const float*)d_in[12];
    const float* Wo   = (const float*)d_in[13];
    const float* bo   = (const float*)d_in[14];
    float* out = (float*)d_out;

    float* ws    = (float*)d_ws;
    float* qg    = ws;                    // 262144
    float* ktg   = qg    + 262144;        // 262144 [b][h][d][512]
    float* vg    = ktg   + 262144;        // 262144
    float* gateg = vg    + 262144;        // 262144
    float* bhg   = gateg + 262144;        // 4194304 [b][h][q][k]

    hipLaunchKernelGGL(kA, dim3(1280), dim3(512), 0, stream,
        x, mask, lng, lnb, Wq, Wk, Wv, Wg, bgv, lnbg, lnbb, Wb, bias, bo,
        qg, ktg, vg, gateg, bhg, out);
    hipLaunchKernelGGL(kB, dim3(256), dim3(512), 0, stream,
        qg, ktg, vg, gateg, bhg, mask, Wo, out);
}

// Round 16
// 76.151 us; speedup vs baseline: 1.1562x; 1.1562x over previous
//
#include <hip/hip_runtime.h>
#include <cstddef>

#define QK_SCALE 0.17677669529663687f   // 1/sqrt(32)

#define FMA4(acc, sc, c) \
    acc.x = fmaf(sc, c.x, acc.x); acc.y = fmaf(sc, c.y, acc.y); \
    acc.z = fmaf(sc, c.z, acc.z); acc.w = fmaf(sc, c.w, acc.w);
#define SCL4(dst, s, v) \
    dst.x = s*v.x; dst.y = s*v.y; dst.z = s*v.z; dst.w = s*v.w;

// 16-lane split-ownership tree reduce (8 head-dots -> 1 per lane)
__device__ __forceinline__ float hred16(float4 dA, float4 dB, int sg) {
    float4 give = (sg & 1) ? dA : dB;
    float4 keep = (sg & 1) ? dB : dA;
    keep.x += __shfl_xor(give.x, 1); keep.y += __shfl_xor(give.y, 1);
    keep.z += __shfl_xor(give.z, 1); keep.w += __shfl_xor(give.w, 1);
    float g0 = (sg & 2) ? keep.x : keep.z;
    float g1 = (sg & 2) ? keep.y : keep.w;
    float e0 = (sg & 2) ? keep.z : keep.x;
    float e1 = (sg & 2) ? keep.w : keep.y;
    e0 += __shfl_xor(g0, 2); e1 += __shfl_xor(g1, 2);
    float g2 = (sg & 4) ? e0 : e1;
    float d  = (sg & 4) ? e1 : e0;
    d += __shfl_xor(g2, 4);
    d += __shfl_xor(d, 8);
    return d;
}

// ================= KA: [0,256) proj + out-init ; [256,2304) bias-LN @Wb =================
__global__ __launch_bounds__(256) void kA(
    const float* __restrict__ x, const int* __restrict__ mask,
    const float* __restrict__ lng, const float* __restrict__ lnb,
    const float* __restrict__ Wq, const float* __restrict__ Wk,
    const float* __restrict__ Wv, const float* __restrict__ Wg,
    const float* __restrict__ bgv,
    const float* __restrict__ lnbg, const float* __restrict__ lnbb,
    const float* __restrict__ Wb, const float* __restrict__ bias,
    const float* __restrict__ bo,
    float* __restrict__ qg, float* __restrict__ ktg,
    float* __restrict__ vg, float* __restrict__ gateg,
    float* __restrict__ bh, float* __restrict__ out)
{
    __shared__ float xn_s[4][256];
    __shared__ int kl_s[512];
    __shared__ int cnt_s[8];
    const int tid = threadIdx.x;
    const int w = tid >> 6, lane = tid & 63;

    if (blockIdx.x >= 256) {
        // ---------------- bias path: block = (b, q, k-half) ----------------
        const int bid2 = blockIdx.x - 256;
        const int b    = bid2 >> 10;
        const int q    = (bid2 >> 1) & 511;
        const int half = bid2 & 1;
        if (mask[(b << 9) + q] == 0) return;          // block-uniform exit

        // in-block compaction of unmasked k
        int mreg[2]; unsigned long long bal[2];
        #pragma unroll
        for (int c = 0; c < 2; ++c) {
            mreg[c] = (mask[(b << 9) + c*256 + tid] != 0);
            bal[c] = __ballot(mreg[c]);
            if (lane == 0) cnt_s[(c << 2) + w] = __popcll(bal[c]);
        }
        __syncthreads();
        int nk = 0;
        #pragma unroll
        for (int j = 0; j < 8; ++j) nk += cnt_s[j];
        #pragma unroll
        for (int c = 0; c < 2; ++c) {
            int idx = (c << 2) + w, base = 0;
            #pragma unroll
            for (int j = 0; j < 8; ++j) base += (j < idx) ? cnt_s[j] : 0;
            if (mreg[c])
                kl_s[base + __popcll(bal[c] & ((1ull << lane) - 1ull))] = c*256 + tid;
        }

        // per-lane coefficients + S1/S2, computed from Wb/lnbg/lnbb directly
        const int rq = lane >> 4;
        const int sg = lane & 15;
        const int h  = ((sg & 1) << 2) + (sg & 2) + ((sg >> 2) & 1);
        float4 cA0[4], cB0[4], cA1[4], cB1[4];
        float4 s1a = {0,0,0,0}, s1b = {0,0,0,0}, s2a = {0,0,0,0}, s2b = {0,0,0,0};
        #pragma unroll
        for (int j = 0; j < 4; ++j) {
            int c0 = 4*sg + j, c1 = 64 + 4*sg + j;
            float4 wa = *reinterpret_cast<const float4*>(Wb + c0*8);
            float4 wb = *reinterpret_cast<const float4*>(Wb + c0*8 + 4);
            float ga = lnbg[c0], bbv = lnbb[c0];
            SCL4(cA0[j], ga, wa); SCL4(cB0[j], ga, wb);
            FMA4(s1a, ga, wa); FMA4(s1b, ga, wb);
            FMA4(s2a, bbv, wa); FMA4(s2b, bbv, wb);
            float4 wa1 = *reinterpret_cast<const float4*>(Wb + c1*8);
            float4 wb1 = *reinterpret_cast<const float4*>(Wb + c1*8 + 4);
            float ga1 = lnbg[c1], bbv1 = lnbb[c1];
            SCL4(cA1[j], ga1, wa1); SCL4(cB1[j], ga1, wb1);
            FMA4(s1a, ga1, wa1); FMA4(s1b, ga1, wb1);
            FMA4(s2a, bbv1, wa1); FMA4(s2b, bbv1, wb1);
        }
        const float S1 = hred16(s1a, s1b, sg);
        const float S2 = hred16(s2a, s2b, sg);

        const float4* brow = reinterpret_cast<const float4*>(
            bias + (size_t)((b << 9) + q) * 512 * 128);
        __syncthreads();

        for (int p = 0; (p << 5) + half < nk; ++p) {
            const int i = (((p << 4) + (w << 2) + rq) << 1) + half;
            if (i < nk) {
                const int k = kl_s[i];
                const float4* bp = brow + (size_t)k * 32;
                float4 v0 = bp[sg];
                float4 v1 = bp[16 + sg];

                float s  = v0.x+v0.y+v0.z+v0.w + v1.x+v1.y+v1.z+v1.w;
                float ss = v0.x*v0.x; ss = fmaf(v0.y,v0.y, ss); ss = fmaf(v0.z,v0.z, ss);
                ss = fmaf(v0.w,v0.w, ss); ss = fmaf(v1.x,v1.x, ss); ss = fmaf(v1.y,v1.y, ss);
                ss = fmaf(v1.z,v1.z, ss); ss = fmaf(v1.w,v1.w, ss);

                float4 dA = {0.f,0.f,0.f,0.f}, dB = {0.f,0.f,0.f,0.f};
                FMA4(dA, v0.x, cA0[0]); FMA4(dB, v0.x, cB0[0]);
                FMA4(dA, v0.y, cA0[1]); FMA4(dB, v0.y, cB0[1]);
                FMA4(dA, v0.z, cA0[2]); FMA4(dB, v0.z, cB0[2]);
                FMA4(dA, v0.w, cA0[3]); FMA4(dB, v0.w, cB0[3]);
                FMA4(dA, v1.x, cA1[0]); FMA4(dB, v1.x, cB1[0]);
                FMA4(dA, v1.y, cA1[1]); FMA4(dB, v1.y, cB1[1]);
                FMA4(dA, v1.z, cA1[2]); FMA4(dB, v1.z, cB1[2]);
                FMA4(dA, v1.w, cA1[3]); FMA4(dB, v1.w, cB1[3]);

                float dsum = hred16(dA, dB, sg);
                #pragma unroll
                for (int m = 1; m < 16; m <<= 1) {
                    s  += __shfl_xor(s,  m);
                    ss += __shfl_xor(ss, m);
                }
                float mean = s * (1.f/128.f);
                float rstd = rsqrtf(ss*(1.f/128.f) - mean*mean + 1e-5f);
                if (sg < 8)
                    bh[((size_t)((b*8 + h) * 512) + q) * 512 + k] = rstd * (dsum - mean*S1) + S2;
            }
        }
        return;
    }

    // ---------------- proj path: 4 rows + out-init ----------------
    const int gr0 = blockIdx.x * 4;
    const int row = gr0 + w;

    float4 xv = *reinterpret_cast<const float4*>(x + (size_t)row * 256 + lane * 4);
    float s  = xv.x + xv.y + xv.z + xv.w;
    float ss = xv.x*xv.x + xv.y*xv.y + xv.z*xv.z + xv.w*xv.w;
    #pragma unroll
    for (int m = 1; m < 64; m <<= 1) { s += __shfl_xor(s, m); ss += __shfl_xor(ss, m); }
    float mean = s * (1.f/256.f);
    float rstd = rsqrtf(ss*(1.f/256.f) - mean*mean + 1e-5f);
    float4 g4 = *reinterpret_cast<const float4*>(lng + lane*4);
    float4 b4 = *reinterpret_cast<const float4*>(lnb + lane*4);
    float4 xn;
    xn.x = (xv.x-mean)*rstd*g4.x + b4.x;
    xn.y = (xv.y-mean)*rstd*g4.y + b4.y;
    xn.z = (xv.z-mean)*rstd*g4.z + b4.z;
    xn.w = (xv.w-mean)*rstd*g4.w + b4.w;
    *reinterpret_cast<float4*>(&xn_s[w][lane*4]) = xn;

    // out init: bo for unmasked rows, 0 for masked (KB atomically adds head terms)
    float bov = bo[tid];
    #pragma unroll
    for (int r = 0; r < 4; ++r) {
        int gr = gr0 + r;
        out[(size_t)gr * 256 + tid] = (mask[gr] == 0) ? 0.f : bov;
    }
    __syncthreads();

    const float* W = (w == 0) ? Wq : (w == 1) ? Wk : (w == 2) ? Wv : Wg;
    const int col = lane << 2;
    float a[4][4];
    #pragma unroll
    for (int r = 0; r < 4; ++r)
        #pragma unroll
        for (int c = 0; c < 4; ++c) a[r][c] = 0.f;

    #pragma unroll 4
    for (int c = 0; c < 256; c += 4) {
        float4 w0 = *reinterpret_cast<const float4*>(W + (size_t)(c+0)*256 + col);
        float4 w1 = *reinterpret_cast<const float4*>(W + (size_t)(c+1)*256 + col);
        float4 w2 = *reinterpret_cast<const float4*>(W + (size_t)(c+2)*256 + col);
        float4 w3 = *reinterpret_cast<const float4*>(W + (size_t)(c+3)*256 + col);
        #pragma unroll
        for (int r = 0; r < 4; ++r) {
            float4 xr = *reinterpret_cast<const float4*>(&xn_s[r][c]);
            a[r][0] = fmaf(xr.x,w0.x, fmaf(xr.y,w1.x, fmaf(xr.z,w2.x, fmaf(xr.w,w3.x, a[r][0]))));
            a[r][1] = fmaf(xr.x,w0.y, fmaf(xr.y,w1.y, fmaf(xr.z,w2.y, fmaf(xr.w,w3.y, a[r][1]))));
            a[r][2] = fmaf(xr.x,w0.z, fmaf(xr.y,w1.z, fmaf(xr.z,w2.z, fmaf(xr.w,w3.z, a[r][2]))));
            a[r][3] = fmaf(xr.x,w0.w, fmaf(xr.y,w1.w, fmaf(xr.z,w2.w, fmaf(xr.w,w3.w, a[r][3]))));
        }
    }

    if (w == 0) {
        #pragma unroll
        for (int r = 0; r < 4; ++r) {
            float4 o; o.x=a[r][0]; o.y=a[r][1]; o.z=a[r][2]; o.w=a[r][3];
            *reinterpret_cast<float4*>(qg + (size_t)(gr0+r)*256 + col) = o;
        }
    } else if (w == 1) {
        #pragma unroll
        for (int r = 0; r < 4; ++r) {
            int gr = gr0 + r, gb = gr >> 9, gl = gr & 511;
            #pragma unroll
            for (int jj = 0; jj < 4; ++jj) {
                int c2 = col + jj;
                ktg[((size_t)(gb*8 + (c2>>5))*32 + (c2&31))*512 + gl] = a[r][jj] * QK_SCALE;
            }
        }
    } else if (w == 2) {
        #pragma unroll
        for (int r = 0; r < 4; ++r) {
            float4 o; o.x=a[r][0]; o.y=a[r][1]; o.z=a[r][2]; o.w=a[r][3];
            *reinterpret_cast<float4*>(vg + (size_t)(gr0+r)*256 + col) = o;
        }
    } else {
        float4 bg4 = *reinterpret_cast<const float4*>(bgv + col);
        #pragma unroll
        for (int r = 0; r < 4; ++r) {
            float4 o;
            o.x = 1.f/(1.f + __expf(-(a[r][0] + bg4.x)));
            o.y = 1.f/(1.f + __expf(-(a[r][1] + bg4.y)));
            o.z = 1.f/(1.f + __expf(-(a[r][2] + bg4.z)));
            o.w = 1.f/(1.f + __expf(-(a[r][3] + bg4.w)));
            *reinterpret_cast<float4*>(gateg + (size_t)(gr0+r)*256 + col) = o;
        }
    }
}

// ================= KB: attention per (b,h,32q) + fused Wo epilogue (atomicAdd) =========
__global__ __launch_bounds__(512, 2) void kB(
    const float* __restrict__ qg, const float* __restrict__ ktg,
    const float* __restrict__ vg, const float* __restrict__ gateg,
    const float* __restrict__ bh, const int* __restrict__ mask,
    const float* __restrict__ Wo, float* __restrict__ out)
{
    __shared__ float kv_s[8192];        // K [32][128] | V [128][32]; reused for Wo slice
    __shared__ float q_s[32][32];
    __shared__ float p_s[8][4][128];
    __shared__ float att_s[32][32];

    const int tid = threadIdx.x;
    const int bid = blockIdx.x;
    const int b  = bid >> 7;
    const int h  = (bid >> 4) & 7;
    const int qt = bid & 15;
    const int w = tid >> 6, lane = tid & 63;
    const int ql = lane >> 5, dd2 = lane & 31;
    const int mq = b << 9;
    const int q0 = qt << 5;
    const int qw = q0 + (w << 2);

    {
        int qr = tid >> 4, dd = (tid & 15) << 1;
        float2 v = *reinterpret_cast<const float2*>(
            qg + (size_t)(mq + q0 + qr) * 256 + (h << 5) + dd);
        *reinterpret_cast<float2*>(&q_s[qr][dd]) = v;
    }

    float mrun[4] = {-1e30f, -1e30f, -1e30f, -1e30f};
    float sden[4] = {0.f, 0.f, 0.f, 0.f};
    float a0A=0.f, a0B=0.f, a1A=0.f, a1B=0.f;

    for (int kt2 = 0; kt2 < 4; ++kt2) {
        const int k0 = kt2 << 7;
        __syncthreads();
        {
            int d = tid >> 4, kk = (tid & 15) << 3;
            const float* src = ktg + ((size_t)((b << 3) + h) * 32 + d) * 512 + k0 + kk;
            float4 a4 = *reinterpret_cast<const float4*>(src);
            float4 b4 = *reinterpret_cast<const float4*>(src + 4);
            *reinterpret_cast<float4*>(&kv_s[d * 128 + kk])     = a4;
            *reinterpret_cast<float4*>(&kv_s[d * 128 + kk + 4]) = b4;
            int k = tid >> 2, dd = (tid & 3) << 3;
            const float* vs = vg + (size_t)(mq + k0 + k) * 256 + (h << 5) + dd;
            float4 c4 = *reinterpret_cast<const float4*>(vs);
            float4 e4 = *reinterpret_cast<const float4*>(vs + 4);
            *reinterpret_cast<float4*>(&kv_s[4096 + k * 32 + dd])     = c4;
            *reinterpret_cast<float4*>(&kv_s[4096 + k * 32 + dd + 4]) = e4;
        }
        __syncthreads();

        const int mkA = (mask[mq + k0 + lane] == 0);
        const int mkB = (mask[mq + k0 + 64 + lane] == 0);

        float bhA[4], bhB[4];
        #pragma unroll
        for (int qq = 0; qq < 4; ++qq) {
            const float* r = bh + (((size_t)(b*8 + h) * 512) + qw + qq) * 512 + k0;
            bhA[qq] = r[lane];
            bhB[qq] = r[64 + lane];
        }

        float lA[4] = {0.f,0.f,0.f,0.f}, lB[4] = {0.f,0.f,0.f,0.f};
        #pragma unroll
        for (int d4 = 0; d4 < 32; d4 += 4) {
            float4 q4[4];
            #pragma unroll
            for (int qq = 0; qq < 4; ++qq)
                q4[qq] = *reinterpret_cast<const float4*>(&q_s[(w << 2) + qq][d4]);
            float kv0[4], kv1[4];
            #pragma unroll
            for (int j = 0; j < 4; ++j) {
                kv0[j] = kv_s[(d4 + j) * 128 + lane];
                kv1[j] = kv_s[(d4 + j) * 128 + 64 + lane];
            }
            #pragma unroll
            for (int qq = 0; qq < 4; ++qq) {
                lA[qq] = fmaf(q4[qq].x, kv0[0], lA[qq]);
                lA[qq] = fmaf(q4[qq].y, kv0[1], lA[qq]);
                lA[qq] = fmaf(q4[qq].z, kv0[2], lA[qq]);
                lA[qq] = fmaf(q4[qq].w, kv0[3], lA[qq]);
                lB[qq] = fmaf(q4[qq].x, kv1[0], lB[qq]);
                lB[qq] = fmaf(q4[qq].y, kv1[1], lB[qq]);
                lB[qq] = fmaf(q4[qq].z, kv1[2], lB[qq]);
                lB[qq] = fmaf(q4[qq].w, kv1[3], lB[qq]);
            }
        }

        float corr4[4];
        #pragma unroll
        for (int qq = 0; qq < 4; ++qq) {
            float la = mkA ? -1e30f : (lA[qq] + bhA[qq]);
            float lb = mkB ? -1e30f : (lB[qq] + bhB[qq]);
            float mx = fmaxf(la, lb);
            #pragma unroll
            for (int m = 1; m < 64; m <<= 1) mx = fmaxf(mx, __shfl_xor(mx, m));
            float mnew = fmaxf(mrun[qq], mx);
            float corr = __expf(mrun[qq] - mnew);
            float pa = mkA ? 0.f : __expf(la - mnew);
            float pb = mkB ? 0.f : __expf(lb - mnew);
            float ts = pa + pb;
            #pragma unroll
            for (int m = 1; m < 64; m <<= 1) ts += __shfl_xor(ts, m);
            sden[qq] = sden[qq] * corr + ts;
            mrun[qq] = mnew;
            corr4[qq] = corr;
            p_s[w][qq][lane]      = pa;
            p_s[w][qq][64 + lane] = pb;
        }

        float c0 = ql ? corr4[1] : corr4[0];
        float c1 = ql ? corr4[3] : corr4[2];
        a0A *= c0; a0B *= c0; a1A *= c1; a1B *= c1;
        const float* pr0 = p_s[w][ql];
        const float* pr1 = p_s[w][ql + 2];
        #pragma unroll 4
        for (int k = 0; k < 128; k += 8) {
            float4 p0a = *reinterpret_cast<const float4*>(pr0 + k);
            float4 p0b = *reinterpret_cast<const float4*>(pr0 + k + 4);
            float4 p1a = *reinterpret_cast<const float4*>(pr1 + k);
            float4 p1b = *reinterpret_cast<const float4*>(pr1 + k + 4);
            float v0 = kv_s[4096 + (k+0)*32 + dd2], v1 = kv_s[4096 + (k+1)*32 + dd2];
            float v2 = kv_s[4096 + (k+2)*32 + dd2], v3 = kv_s[4096 + (k+3)*32 + dd2];
            float v4 = kv_s[4096 + (k+4)*32 + dd2], v5 = kv_s[4096 + (k+5)*32 + dd2];
            float v6 = kv_s[4096 + (k+6)*32 + dd2], v7 = kv_s[4096 + (k+7)*32 + dd2];
            a0A = fmaf(p0a.x,v0, fmaf(p0a.y,v1, fmaf(p0a.z,v2, fmaf(p0a.w,v3, a0A))));
            a0B = fmaf(p0b.x,v4, fmaf(p0b.y,v5, fmaf(p0b.z,v6, fmaf(p0b.w,v7, a0B))));
            a1A = fmaf(p1a.x,v0, fmaf(p1a.y,v1, fmaf(p1a.z,v2, fmaf(p1a.w,v3, a1A))));
            a1B = fmaf(p1b.x,v4, fmaf(p1b.y,v5, fmaf(p1b.z,v6, fmaf(p1b.w,v7, a1B))));
        }
    }

    // ---- gated, normalized head output -> LDS (masked q rows -> 0, guards NaN) ----
    {
        float sd0 = ql ? sden[1] : sden[0];
        float sd1 = ql ? sden[3] : sden[2];
        float g0 = gateg[(size_t)(mq + qw + ql) * 256 + (h << 5) + dd2];
        float g1 = gateg[(size_t)(mq + qw + ql + 2) * 256 + (h << 5) + dd2];
        int iv0 = (mask[mq + qw + ql] == 0);
        int iv1 = (mask[mq + qw + ql + 2] == 0);
        att_s[(w << 2) + ql][dd2]     = iv0 ? 0.f : (a0A + a0B) / sd0 * g0;
        att_s[(w << 2) + ql + 2][dd2] = iv1 ? 0.f : (a1A + a1B) / sd1 * g1;
    }
    __syncthreads();

    // ---- stage Wo head-slice [32][256] into kv_s (K/V space now free) ----
    {
        const float* wsrc = Wo + (size_t)h * 32 * 256;
        for (int i = tid; i < 2048; i += 512)
            *reinterpret_cast<float4*>(&kv_s[i << 2]) =
                *reinterpret_cast<const float4*>(wsrc + (i << 2));
    }
    __syncthreads();

    // ---- per-head partial of att @ Wo, atomically accumulated into out ----
    {
        const int c2 = tid & 255, qh = tid >> 8;   // qh in {0,1}: rows qh*16..+15
        float acc[16];
        #pragma unroll
        for (int i = 0; i < 16; ++i) acc[i] = 0.f;
        #pragma unroll
        for (int d4 = 0; d4 < 32; d4 += 4) {
            float w0 = kv_s[(d4+0)*256 + c2];
            float w1 = kv_s[(d4+1)*256 + c2];
            float w2 = kv_s[(d4+2)*256 + c2];
            float w3 = kv_s[(d4+3)*256 + c2];
            #pragma unroll
            for (int i = 0; i < 16; ++i) {
                float4 a4 = *reinterpret_cast<const float4*>(&att_s[(qh << 4) + i][d4]);
                acc[i] = fmaf(a4.x,w0, fmaf(a4.y,w1, fmaf(a4.z,w2, fmaf(a4.w,w3, acc[i]))));
            }
        }
        #pragma unroll
        for (int i = 0; i < 16; ++i)
            atomicAdd(out + (size_t)(mq + q0 + (qh << 4) + i) * 256 + c2, acc[i]);
    }
}

extern "C" void kernel_launch(void* const* d_in, const int* in_sizes, int n_in,
                              void* d_out, int out_size, void* d_ws, size_t ws_size,
                              hipStream_t stream)
{
    const float* x    = (const float*)d_in[0];
    const float* bias = (const float*)d_in[1];
    const int*   mask = (const int*)d_in[2];
    const float* lng  = (const float*)d_in[3];
    const float* lnb  = (const float*)d_in[4];
    const float* lnbg = (const float*)d_in[5];
    const float* lnbb = (const float*)d_in[6];
    const float* Wq   = (const float*)d_in[7];
    const float* Wk   = (const float*)d_in[8];
    const float* Wv   = (const float*)d_in[9];
    const float* Wb   = (const float*)d_in[10];
    const float* Wg   = (const float*)d_in[11];
    const float* bgv  = (const float*)d_in[12];
    const float* Wo   = (const float*)d_in[13];
    const float* bo   = (const float*)d_in[14];
    float* out = (float*)d_out;

    float* ws    = (float*)d_ws;
    float* qg    = ws;                    // 262144
    float* ktg   = qg    + 262144;        // 262144 [b][h][d][512]
    float* vg    = ktg   + 262144;        // 262144
    float* gateg = vg    + 262144;        // 262144
    float* bhg   = gateg + 262144;        // 4194304 [b][h][q][k]

    hipLaunchKernelGGL(kA, dim3(2304), dim3(256), 0, stream,
        x, mask, lng, lnb, Wq, Wk, Wv, Wg, bgv, lnbg, lnbb, Wb, bias, bo,
        qg, ktg, vg, gateg, bhg, out);
    hipLaunchKernelGGL(kB, dim3(256), dim3(512), 0, stream,
        qg, ktg, vg, gateg, bhg, mask, Wo, out);
}

// Round 17
// 74.243 us; speedup vs baseline: 1.1859x; 1.0257x over previous
//
#include <hip/hip_runtime.h>
#include <cstddef>

#define QK_SCALE 0.17677669529663687f   // 1/sqrt(32)

#define FMA4(acc, sc, c) \
    acc.x = fmaf(sc, c.x, acc.x); acc.y = fmaf(sc, c.y, acc.y); \
    acc.z = fmaf(sc, c.z, acc.z); acc.w = fmaf(sc, c.w, acc.w);
#define SCL4(dst, s, v) \
    dst.x = s*v.x; dst.y = s*v.y; dst.z = s*v.z; dst.w = s*v.w;

// 16-lane split-ownership tree reduce (8 head-dots -> 1 per lane)
__device__ __forceinline__ float hred16(float4 dA, float4 dB, int sg) {
    float4 give = (sg & 1) ? dA : dB;
    float4 keep = (sg & 1) ? dB : dA;
    keep.x += __shfl_xor(give.x, 1); keep.y += __shfl_xor(give.y, 1);
    keep.z += __shfl_xor(give.z, 1); keep.w += __shfl_xor(give.w, 1);
    float g0 = (sg & 2) ? keep.x : keep.z;
    float g1 = (sg & 2) ? keep.y : keep.w;
    float e0 = (sg & 2) ? keep.z : keep.x;
    float e1 = (sg & 2) ? keep.w : keep.y;
    e0 += __shfl_xor(g0, 2); e1 += __shfl_xor(g1, 2);
    float g2 = (sg & 4) ? e0 : e1;
    float d  = (sg & 4) ? e1 : e0;
    d += __shfl_xor(g2, 4);
    d += __shfl_xor(d, 8);
    return d;
}

// ================= KA: [0,256) proj + out-init ; [256,2304) bias-LN @Wb =================
// launch_bounds(256, 4): 4 waves/SIMD floor -> 128-VGPR budget, no scratch spill
// (R13 counters showed VGPR=64 + ~12 MB/rep spill at the default heuristic).
__global__ __launch_bounds__(256, 4) void kA(
    const float* __restrict__ x, const int* __restrict__ mask,
    const float* __restrict__ lng, const float* __restrict__ lnb,
    const float* __restrict__ Wq, const float* __restrict__ Wk,
    const float* __restrict__ Wv, const float* __restrict__ Wg,
    const float* __restrict__ bgv,
    const float* __restrict__ lnbg, const float* __restrict__ lnbb,
    const float* __restrict__ Wb, const float* __restrict__ bias,
    const float* __restrict__ bo,
    float* __restrict__ qg, float* __restrict__ ktg,
    float* __restrict__ vg, float* __restrict__ gateg,
    float* __restrict__ bh, float* __restrict__ out)
{
    __shared__ float xn_s[4][256];
    __shared__ int kl_s[512];
    __shared__ int cnt_s[8];
    const int tid = threadIdx.x;
    const int w = tid >> 6, lane = tid & 63;

    if (blockIdx.x >= 256) {
        // ---------------- bias path: block = (b, q, k-half) ----------------
        const int bid2 = blockIdx.x - 256;
        const int b    = bid2 >> 10;
        const int q    = (bid2 >> 1) & 511;
        const int half = bid2 & 1;
        if (mask[(b << 9) + q] == 0) return;          // block-uniform exit

        // in-block compaction of unmasked k
        int mreg[2]; unsigned long long bal[2];
        #pragma unroll
        for (int c = 0; c < 2; ++c) {
            mreg[c] = (mask[(b << 9) + c*256 + tid] != 0);
            bal[c] = __ballot(mreg[c]);
            if (lane == 0) cnt_s[(c << 2) + w] = __popcll(bal[c]);
        }
        __syncthreads();
        int nk = 0;
        #pragma unroll
        for (int j = 0; j < 8; ++j) nk += cnt_s[j];
        #pragma unroll
        for (int c = 0; c < 2; ++c) {
            int idx = (c << 2) + w, base = 0;
            #pragma unroll
            for (int j = 0; j < 8; ++j) base += (j < idx) ? cnt_s[j] : 0;
            if (mreg[c])
                kl_s[base + __popcll(bal[c] & ((1ull << lane) - 1ull))] = c*256 + tid;
        }

        // per-lane coefficients + S1/S2, computed from Wb/lnbg/lnbb directly
        const int rq = lane >> 4;
        const int sg = lane & 15;
        const int h  = ((sg & 1) << 2) + (sg & 2) + ((sg >> 2) & 1);
        float4 cA0[4], cB0[4], cA1[4], cB1[4];
        float4 s1a = {0,0,0,0}, s1b = {0,0,0,0}, s2a = {0,0,0,0}, s2b = {0,0,0,0};
        #pragma unroll
        for (int j = 0; j < 4; ++j) {
            int c0 = 4*sg + j, c1 = 64 + 4*sg + j;
            float4 wa = *reinterpret_cast<const float4*>(Wb + c0*8);
            float4 wb = *reinterpret_cast<const float4*>(Wb + c0*8 + 4);
            float ga = lnbg[c0], bbv = lnbb[c0];
            SCL4(cA0[j], ga, wa); SCL4(cB0[j], ga, wb);
            FMA4(s1a, ga, wa); FMA4(s1b, ga, wb);
            FMA4(s2a, bbv, wa); FMA4(s2b, bbv, wb);
            float4 wa1 = *reinterpret_cast<const float4*>(Wb + c1*8);
            float4 wb1 = *reinterpret_cast<const float4*>(Wb + c1*8 + 4);
            float ga1 = lnbg[c1], bbv1 = lnbb[c1];
            SCL4(cA1[j], ga1, wa1); SCL4(cB1[j], ga1, wb1);
            FMA4(s1a, ga1, wa1); FMA4(s1b, ga1, wb1);
            FMA4(s2a, bbv1, wa1); FMA4(s2b, bbv1, wb1);
        }
        const float S1 = hred16(s1a, s1b, sg);
        const float S2 = hred16(s2a, s2b, sg);

        const float4* brow = reinterpret_cast<const float4*>(
            bias + (size_t)((b << 9) + q) * 512 * 128);
        __syncthreads();

        for (int p = 0; (p << 5) + half < nk; ++p) {
            const int i = (((p << 4) + (w << 2) + rq) << 1) + half;
            if (i < nk) {
                const int k = kl_s[i];
                const float4* bp = brow + (size_t)k * 32;
                float4 v0 = bp[sg];
                float4 v1 = bp[16 + sg];

                float s  = v0.x+v0.y+v0.z+v0.w + v1.x+v1.y+v1.z+v1.w;
                float ss = v0.x*v0.x; ss = fmaf(v0.y,v0.y, ss); ss = fmaf(v0.z,v0.z, ss);
                ss = fmaf(v0.w,v0.w, ss); ss = fmaf(v1.x,v1.x, ss); ss = fmaf(v1.y,v1.y, ss);
                ss = fmaf(v1.z,v1.z, ss); ss = fmaf(v1.w,v1.w, ss);

                float4 dA = {0.f,0.f,0.f,0.f}, dB = {0.f,0.f,0.f,0.f};
                FMA4(dA, v0.x, cA0[0]); FMA4(dB, v0.x, cB0[0]);
                FMA4(dA, v0.y, cA0[1]); FMA4(dB, v0.y, cB0[1]);
                FMA4(dA, v0.z, cA0[2]); FMA4(dB, v0.z, cB0[2]);
                FMA4(dA, v0.w, cA0[3]); FMA4(dB, v0.w, cB0[3]);
                FMA4(dA, v1.x, cA1[0]); FMA4(dB, v1.x, cB1[0]);
                FMA4(dA, v1.y, cA1[1]); FMA4(dB, v1.y, cB1[1]);
                FMA4(dA, v1.z, cA1[2]); FMA4(dB, v1.z, cB1[2]);
                FMA4(dA, v1.w, cA1[3]); FMA4(dB, v1.w, cB1[3]);

                float dsum = hred16(dA, dB, sg);
                #pragma unroll
                for (int m = 1; m < 16; m <<= 1) {
                    s  += __shfl_xor(s,  m);
                    ss += __shfl_xor(ss, m);
                }
                float mean = s * (1.f/128.f);
                float rstd = rsqrtf(ss*(1.f/128.f) - mean*mean + 1e-5f);
                if (sg < 8)
                    bh[((size_t)((b*8 + h) * 512) + q) * 512 + k] = rstd * (dsum - mean*S1) + S2;
            }
        }
        return;
    }

    // ---------------- proj path: 4 rows + out-init ----------------
    const int gr0 = blockIdx.x * 4;
    const int row = gr0 + w;

    float4 xv = *reinterpret_cast<const float4*>(x + (size_t)row * 256 + lane * 4);
    float s  = xv.x + xv.y + xv.z + xv.w;
    float ss = xv.x*xv.x + xv.y*xv.y + xv.z*xv.z + xv.w*xv.w;
    #pragma unroll
    for (int m = 1; m < 64; m <<= 1) { s += __shfl_xor(s, m); ss += __shfl_xor(ss, m); }
    float mean = s * (1.f/256.f);
    float rstd = rsqrtf(ss*(1.f/256.f) - mean*mean + 1e-5f);
    float4 g4 = *reinterpret_cast<const float4*>(lng + lane*4);
    float4 b4 = *reinterpret_cast<const float4*>(lnb + lane*4);
    float4 xn;
    xn.x = (xv.x-mean)*rstd*g4.x + b4.x;
    xn.y = (xv.y-mean)*rstd*g4.y + b4.y;
    xn.z = (xv.z-mean)*rstd*g4.z + b4.z;
    xn.w = (xv.w-mean)*rstd*g4.w + b4.w;
    *reinterpret_cast<float4*>(&xn_s[w][lane*4]) = xn;

    // out init: bo for unmasked rows, 0 for masked (KB atomically adds head terms)
    float bov = bo[tid];
    #pragma unroll
    for (int r = 0; r < 4; ++r) {
        int gr = gr0 + r;
        out[(size_t)gr * 256 + tid] = (mask[gr] == 0) ? 0.f : bov;
    }
    __syncthreads();

    const float* W = (w == 0) ? Wq : (w == 1) ? Wk : (w == 2) ? Wv : Wg;
    const int col = lane << 2;
    float a[4][4];
    #pragma unroll
    for (int r = 0; r < 4; ++r)
        #pragma unroll
        for (int c = 0; c < 4; ++c) a[r][c] = 0.f;

    #pragma unroll 4
    for (int c = 0; c < 256; c += 4) {
        float4 w0 = *reinterpret_cast<const float4*>(W + (size_t)(c+0)*256 + col);
        float4 w1 = *reinterpret_cast<const float4*>(W + (size_t)(c+1)*256 + col);
        float4 w2 = *reinterpret_cast<const float4*>(W + (size_t)(c+2)*256 + col);
        float4 w3 = *reinterpret_cast<const float4*>(W + (size_t)(c+3)*256 + col);
        #pragma unroll
        for (int r = 0; r < 4; ++r) {
            float4 xr = *reinterpret_cast<const float4*>(&xn_s[r][c]);
            a[r][0] = fmaf(xr.x,w0.x, fmaf(xr.y,w1.x, fmaf(xr.z,w2.x, fmaf(xr.w,w3.x, a[r][0]))));
            a[r][1] = fmaf(xr.x,w0.y, fmaf(xr.y,w1.y, fmaf(xr.z,w2.y, fmaf(xr.w,w3.y, a[r][1]))));
            a[r][2] = fmaf(xr.x,w0.z, fmaf(xr.y,w1.z, fmaf(xr.z,w2.z, fmaf(xr.w,w3.z, a[r][2]))));
            a[r][3] = fmaf(xr.x,w0.w, fmaf(xr.y,w1.w, fmaf(xr.z,w2.w, fmaf(xr.w,w3.w, a[r][3]))));
        }
    }

    if (w == 0) {
        #pragma unroll
        for (int r = 0; r < 4; ++r) {
            float4 o; o.x=a[r][0]; o.y=a[r][1]; o.z=a[r][2]; o.w=a[r][3];
            *reinterpret_cast<float4*>(qg + (size_t)(gr0+r)*256 + col) = o;
        }
    } else if (w == 1) {
        #pragma unroll
        for (int r = 0; r < 4; ++r) {
            int gr = gr0 + r, gb = gr >> 9, gl = gr & 511;
            #pragma unroll
            for (int jj = 0; jj < 4; ++jj) {
                int c2 = col + jj;
                ktg[((size_t)(gb*8 + (c2>>5))*32 + (c2&31))*512 + gl] = a[r][jj] * QK_SCALE;
            }
        }
    } else if (w == 2) {
        #pragma unroll
        for (int r = 0; r < 4; ++r) {
            float4 o; o.x=a[r][0]; o.y=a[r][1]; o.z=a[r][2]; o.w=a[r][3];
            *reinterpret_cast<float4*>(vg + (size_t)(gr0+r)*256 + col) = o;
        }
    } else {
        float4 bg4 = *reinterpret_cast<const float4*>(bgv + col);
        #pragma unroll
        for (int r = 0; r < 4; ++r) {
            float4 o;
            o.x = 1.f/(1.f + __expf(-(a[r][0] + bg4.x)));
            o.y = 1.f/(1.f + __expf(-(a[r][1] + bg4.y)));
            o.z = 1.f/(1.f + __expf(-(a[r][2] + bg4.z)));
            o.w = 1.f/(1.f + __expf(-(a[r][3] + bg4.w)));
            *reinterpret_cast<float4*>(gateg + (size_t)(gr0+r)*256 + col) = o;
        }
    }
}

// ================= KB: attention per (b,h,32q) + fused Wo epilogue (atomicAdd) =========
__global__ __launch_bounds__(512, 2) void kB(
    const float* __restrict__ qg, const float* __restrict__ ktg,
    const float* __restrict__ vg, const float* __restrict__ gateg,
    const float* __restrict__ bh, const int* __restrict__ mask,
    const float* __restrict__ Wo, float* __restrict__ out)
{
    __shared__ float kv_s[8192];        // K [32][128] | V [128][32]; reused for Wo slice
    __shared__ float q_s[32][32];
    __shared__ float p_s[8][4][128];
    __shared__ float att_s[32][32];

    const int tid = threadIdx.x;
    const int bid = blockIdx.x;
    const int b  = bid >> 7;
    const int h  = (bid >> 4) & 7;
    const int qt = bid & 15;
    const int w = tid >> 6, lane = tid & 63;
    const int ql = lane >> 5, dd2 = lane & 31;
    const int mq = b << 9;
    const int q0 = qt << 5;
    const int qw = q0 + (w << 2);

    {
        int qr = tid >> 4, dd = (tid & 15) << 1;
        float2 v = *reinterpret_cast<const float2*>(
            qg + (size_t)(mq + q0 + qr) * 256 + (h << 5) + dd);
        *reinterpret_cast<float2*>(&q_s[qr][dd]) = v;
    }

    float mrun[4] = {-1e30f, -1e30f, -1e30f, -1e30f};
    float sden[4] = {0.f, 0.f, 0.f, 0.f};
    float a0A=0.f, a0B=0.f, a1A=0.f, a1B=0.f;

    for (int kt2 = 0; kt2 < 4; ++kt2) {
        const int k0 = kt2 << 7;
        __syncthreads();
        {
            int d = tid >> 4, kk = (tid & 15) << 3;
            const float* src = ktg + ((size_t)((b << 3) + h) * 32 + d) * 512 + k0 + kk;
            float4 a4 = *reinterpret_cast<const float4*>(src);
            float4 b4 = *reinterpret_cast<const float4*>(src + 4);
            *reinterpret_cast<float4*>(&kv_s[d * 128 + kk])     = a4;
            *reinterpret_cast<float4*>(&kv_s[d * 128 + kk + 4]) = b4;
            int k = tid >> 2, dd = (tid & 3) << 3;
            const float* vs = vg + (size_t)(mq + k0 + k) * 256 + (h << 5) + dd;
            float4 c4 = *reinterpret_cast<const float4*>(vs);
            float4 e4 = *reinterpret_cast<const float4*>(vs + 4);
            *reinterpret_cast<float4*>(&kv_s[4096 + k * 32 + dd])     = c4;
            *reinterpret_cast<float4*>(&kv_s[4096 + k * 32 + dd + 4]) = e4;
        }
        __syncthreads();

        const int mkA = (mask[mq + k0 + lane] == 0);
        const int mkB = (mask[mq + k0 + 64 + lane] == 0);

        float bhA[4], bhB[4];
        #pragma unroll
        for (int qq = 0; qq < 4; ++qq) {
            const float* r = bh + (((size_t)(b*8 + h) * 512) + qw + qq) * 512 + k0;
            bhA[qq] = r[lane];
            bhB[qq] = r[64 + lane];
        }

        float lA[4] = {0.f,0.f,0.f,0.f}, lB[4] = {0.f,0.f,0.f,0.f};
        #pragma unroll
        for (int d4 = 0; d4 < 32; d4 += 4) {
            float4 q4[4];
            #pragma unroll
            for (int qq = 0; qq < 4; ++qq)
                q4[qq] = *reinterpret_cast<const float4*>(&q_s[(w << 2) + qq][d4]);
            float kv0[4], kv1[4];
            #pragma unroll
            for (int j = 0; j < 4; ++j) {
                kv0[j] = kv_s[(d4 + j) * 128 + lane];
                kv1[j] = kv_s[(d4 + j) * 128 + 64 + lane];
            }
            #pragma unroll
            for (int qq = 0; qq < 4; ++qq) {
                lA[qq] = fmaf(q4[qq].x, kv0[0], lA[qq]);
                lA[qq] = fmaf(q4[qq].y, kv0[1], lA[qq]);
                lA[qq] = fmaf(q4[qq].z, kv0[2], lA[qq]);
                lA[qq] = fmaf(q4[qq].w, kv0[3], lA[qq]);
                lB[qq] = fmaf(q4[qq].x, kv1[0], lB[qq]);
                lB[qq] = fmaf(q4[qq].y, kv1[1], lB[qq]);
                lB[qq] = fmaf(q4[qq].z, kv1[2], lB[qq]);
                lB[qq] = fmaf(q4[qq].w, kv1[3], lB[qq]);
            }
        }

        float corr4[4];
        #pragma unroll
        for (int qq = 0; qq < 4; ++qq) {
            float la = mkA ? -1e30f : (lA[qq] + bhA[qq]);
            float lb = mkB ? -1e30f : (lB[qq] + bhB[qq]);
            float mx = fmaxf(la, lb);
            #pragma unroll
            for (int m = 1; m < 64; m <<= 1) mx = fmaxf(mx, __shfl_xor(mx, m));
            float mnew = fmaxf(mrun[qq], mx);
            float corr = __expf(mrun[qq] - mnew);
            float pa = mkA ? 0.f : __expf(la - mnew);
            float pb = mkB ? 0.f : __expf(lb - mnew);
            float ts = pa + pb;
            #pragma unroll
            for (int m = 1; m < 64; m <<= 1) ts += __shfl_xor(ts, m);
            sden[qq] = sden[qq] * corr + ts;
            mrun[qq] = mnew;
            corr4[qq] = corr;
            p_s[w][qq][lane]      = pa;
            p_s[w][qq][64 + lane] = pb;
        }

        float c0 = ql ? corr4[1] : corr4[0];
        float c1 = ql ? corr4[3] : corr4[2];
        a0A *= c0; a0B *= c0; a1A *= c1; a1B *= c1;
        const float* pr0 = p_s[w][ql];
        const float* pr1 = p_s[w][ql + 2];
        #pragma unroll 4
        for (int k = 0; k < 128; k += 8) {
            float4 p0a = *reinterpret_cast<const float4*>(pr0 + k);
            float4 p0b = *reinterpret_cast<const float4*>(pr0 + k + 4);
            float4 p1a = *reinterpret_cast<const float4*>(pr1 + k);
            float4 p1b = *reinterpret_cast<const float4*>(pr1 + k + 4);
            float v0 = kv_s[4096 + (k+0)*32 + dd2], v1 = kv_s[4096 + (k+1)*32 + dd2];
            float v2 = kv_s[4096 + (k+2)*32 + dd2], v3 = kv_s[4096 + (k+3)*32 + dd2];
            float v4 = kv_s[4096 + (k+4)*32 + dd2], v5 = kv_s[4096 + (k+5)*32 + dd2];
            float v6 = kv_s[4096 + (k+6)*32 + dd2], v7 = kv_s[4096 + (k+7)*32 + dd2];
            a0A = fmaf(p0a.x,v0, fmaf(p0a.y,v1, fmaf(p0a.z,v2, fmaf(p0a.w,v3, a0A))));
            a0B = fmaf(p0b.x,v4, fmaf(p0b.y,v5, fmaf(p0b.z,v6, fmaf(p0b.w,v7, a0B))));
            a1A = fmaf(p1a.x,v0, fmaf(p1a.y,v1, fmaf(p1a.z,v2, fmaf(p1a.w,v3, a1A))));
            a1B = fmaf(p1b.x,v4, fmaf(p1b.y,v5, fmaf(p1b.z,v6, fmaf(p1b.w,v7, a1B))));
        }
    }

    // ---- gated, normalized head output -> LDS (masked q rows -> 0, guards NaN) ----
    {
        float sd0 = ql ? sden[1] : sden[0];
        float sd1 = ql ? sden[3] : sden[2];
        float g0 = gateg[(size_t)(mq + qw + ql) * 256 + (h << 5) + dd2];
        float g1 = gateg[(size_t)(mq + qw + ql + 2) * 256 + (h << 5) + dd2];
        int iv0 = (mask[mq + qw + ql] == 0);
        int iv1 = (mask[mq + qw + ql + 2] == 0);
        att_s[(w << 2) + ql][dd2]     = iv0 ? 0.f : (a0A + a0B) / sd0 * g0;
        att_s[(w << 2) + ql + 2][dd2] = iv1 ? 0.f : (a1A + a1B) / sd1 * g1;
    }
    __syncthreads();

    // ---- stage Wo head-slice [32][256] into kv_s (K/V space now free) ----
    {
        const float* wsrc = Wo + (size_t)h * 32 * 256;
        for (int i = tid; i < 2048; i += 512)
            *reinterpret_cast<float4*>(&kv_s[i << 2]) =
                *reinterpret_cast<const float4*>(wsrc + (i << 2));
    }
    __syncthreads();

    // ---- per-head partial of att @ Wo, atomically accumulated into out ----
    {
        const int c2 = tid & 255, qh = tid >> 8;   // qh in {0,1}: rows qh*16..+15
        float acc[16];
        #pragma unroll
        for (int i = 0; i < 16; ++i) acc[i] = 0.f;
        #pragma unroll
        for (int d4 = 0; d4 < 32; d4 += 4) {
            float w0 = kv_s[(d4+0)*256 + c2];
            float w1 = kv_s[(d4+1)*256 + c2];
            float w2 = kv_s[(d4+2)*256 + c2];
            float w3 = kv_s[(d4+3)*256 + c2];
            #pragma unroll
            for (int i = 0; i < 16; ++i) {
                float4 a4 = *reinterpret_cast<const float4*>(&att_s[(qh << 4) + i][d4]);
                acc[i] = fmaf(a4.x,w0, fmaf(a4.y,w1, fmaf(a4.z,w2, fmaf(a4.w,w3, acc[i]))));
            }
        }
        #pragma unroll
        for (int i = 0; i < 16; ++i)
            atomicAdd(out + (size_t)(mq + q0 + (qh << 4) + i) * 256 + c2, acc[i]);
    }
}

extern "C" void kernel_launch(void* const* d_in, const int* in_sizes, int n_in,
                              void* d_out, int out_size, void* d_ws, size_t ws_size,
                              hipStream_t stream)
{
    const float* x    = (const float*)d_in[0];
    const float* bias = (const float*)d_in[1];
    const int*   mask = (const int*)d_in[2];
    const float* lng  = (const float*)d_in[3];
    const float* lnb  = (const float*)d_in[4];
    const float* lnbg = (const float*)d_in[5];
    const float* lnbb = (const float*)d_in[6];
    const float* Wq   = (const float*)d_in[7];
    const float* Wk   = (const float*)d_in[8];
    const float* Wv   = (const float*)d_in[9];
    const float* Wb   = (const float*)d_in[10];
    const float* Wg   = (const float*)d_in[11];
    const float* bgv  = (const float*)d_in[12];
    const float* Wo   = (const float*)d_in[13];
    const float* bo   = (const float*)d_in[14];
    float* out = (float*)d_out;

    float* ws    = (float*)d_ws;
    float* qg    = ws;                    // 262144
    float* ktg   = qg    + 262144;        // 262144 [b][h][d][512]
    float* vg    = ktg   + 262144;        // 262144
    float* gateg = vg    + 262144;        // 262144
    float* bhg   = gateg + 262144;        // 4194304 [b][h][q][k]

    hipLaunchKernelGGL(kA, dim3(2304), dim3(256), 0, stream,
        x, mask, lng, lnb, Wq, Wk, Wv, Wg, bgv, lnbg, lnbb, Wb, bias, bo,
        qg, ktg, vg, gateg, bhg, out);
    hipLaunchKernelGGL(kB, dim3(256), dim3(512), 0, stream,
        qg, ktg, vg, gateg, bhg, mask, Wo, out);
}

// Round 18
// 73.319 us; speedup vs baseline: 1.2009x; 1.0126x over previous
//
#include <hip/hip_runtime.h>
#include <cstddef>

#define QK_SCALE 0.17677669529663687f   // 1/sqrt(32)

#define FMA4(acc, sc, c) \
    acc.x = fmaf(sc, c.x, acc.x); acc.y = fmaf(sc, c.y, acc.y); \
    acc.z = fmaf(sc, c.z, acc.z); acc.w = fmaf(sc, c.w, acc.w);
#define SCL4(dst, s, v) \
    dst.x = s*v.x; dst.y = s*v.y; dst.z = s*v.z; dst.w = s*v.w;

// 16-lane split-ownership tree reduce (8 head-dots -> 1 per lane)
__device__ __forceinline__ float hred16(float4 dA, float4 dB, int sg) {
    float4 give = (sg & 1) ? dA : dB;
    float4 keep = (sg & 1) ? dB : dA;
    keep.x += __shfl_xor(give.x, 1); keep.y += __shfl_xor(give.y, 1);
    keep.z += __shfl_xor(give.z, 1); keep.w += __shfl_xor(give.w, 1);
    float g0 = (sg & 2) ? keep.x : keep.z;
    float g1 = (sg & 2) ? keep.y : keep.w;
    float e0 = (sg & 2) ? keep.z : keep.x;
    float e1 = (sg & 2) ? keep.w : keep.y;
    e0 += __shfl_xor(g0, 2); e1 += __shfl_xor(g1, 2);
    float g2 = (sg & 4) ? e0 : e1;
    float d  = (sg & 4) ? e1 : e0;
    d += __shfl_xor(g2, 4);
    d += __shfl_xor(d, 8);
    return d;
}

// ================= KA: [0,256) proj + out-init ; [256,2304) bias-LN @Wb =================
// launch_bounds(256, 4): 4 waves/SIMD floor -> 128-VGPR budget, no scratch spill
// (R13 counters showed VGPR=64 + ~12 MB/rep spill at the default heuristic).
__global__ __launch_bounds__(256, 4) void kA(
    const float* __restrict__ x, const int* __restrict__ mask,
    const float* __restrict__ lng, const float* __restrict__ lnb,
    const float* __restrict__ Wq, const float* __restrict__ Wk,
    const float* __restrict__ Wv, const float* __restrict__ Wg,
    const float* __restrict__ bgv,
    const float* __restrict__ lnbg, const float* __restrict__ lnbb,
    const float* __restrict__ Wb, const float* __restrict__ bias,
    const float* __restrict__ bo,
    float* __restrict__ qg, float* __restrict__ ktg,
    float* __restrict__ vg, float* __restrict__ gateg,
    float* __restrict__ bh, float* __restrict__ out)
{
    __shared__ float xn_s[4][256];
    __shared__ int kl_s[512];
    __shared__ int cnt_s[8];
    const int tid = threadIdx.x;
    const int w = tid >> 6, lane = tid & 63;

    if (blockIdx.x >= 256) {
        // ---------------- bias path: block = (b, q, k-half) ----------------
        const int bid2 = blockIdx.x - 256;
        const int b    = bid2 >> 10;
        const int q    = (bid2 >> 1) & 511;
        const int half = bid2 & 1;
        if (mask[(b << 9) + q] == 0) return;          // block-uniform exit

        // in-block compaction of unmasked k
        int mreg[2]; unsigned long long bal[2];
        #pragma unroll
        for (int c = 0; c < 2; ++c) {
            mreg[c] = (mask[(b << 9) + c*256 + tid] != 0);
            bal[c] = __ballot(mreg[c]);
            if (lane == 0) cnt_s[(c << 2) + w] = __popcll(bal[c]);
        }
        __syncthreads();
        int nk = 0;
        #pragma unroll
        for (int j = 0; j < 8; ++j) nk += cnt_s[j];
        #pragma unroll
        for (int c = 0; c < 2; ++c) {
            int idx = (c << 2) + w, base = 0;
            #pragma unroll
            for (int j = 0; j < 8; ++j) base += (j < idx) ? cnt_s[j] : 0;
            if (mreg[c])
                kl_s[base + __popcll(bal[c] & ((1ull << lane) - 1ull))] = c*256 + tid;
        }

        // per-lane coefficients + S1/S2, computed from Wb/lnbg/lnbb directly
        const int rq = lane >> 4;
        const int sg = lane & 15;
        const int h  = ((sg & 1) << 2) + (sg & 2) + ((sg >> 2) & 1);
        float4 cA0[4], cB0[4], cA1[4], cB1[4];
        float4 s1a = {0,0,0,0}, s1b = {0,0,0,0}, s2a = {0,0,0,0}, s2b = {0,0,0,0};
        #pragma unroll
        for (int j = 0; j < 4; ++j) {
            int c0 = 4*sg + j, c1 = 64 + 4*sg + j;
            float4 wa = *reinterpret_cast<const float4*>(Wb + c0*8);
            float4 wb = *reinterpret_cast<const float4*>(Wb + c0*8 + 4);
            float ga = lnbg[c0], bbv = lnbb[c0];
            SCL4(cA0[j], ga, wa); SCL4(cB0[j], ga, wb);
            FMA4(s1a, ga, wa); FMA4(s1b, ga, wb);
            FMA4(s2a, bbv, wa); FMA4(s2b, bbv, wb);
            float4 wa1 = *reinterpret_cast<const float4*>(Wb + c1*8);
            float4 wb1 = *reinterpret_cast<const float4*>(Wb + c1*8 + 4);
            float ga1 = lnbg[c1], bbv1 = lnbb[c1];
            SCL4(cA1[j], ga1, wa1); SCL4(cB1[j], ga1, wb1);
            FMA4(s1a, ga1, wa1); FMA4(s1b, ga1, wb1);
            FMA4(s2a, bbv1, wa1); FMA4(s2b, bbv1, wb1);
        }
        const float S1 = hred16(s1a, s1b, sg);
        const float S2 = hred16(s2a, s2b, sg);

        const float4* brow = reinterpret_cast<const float4*>(
            bias + (size_t)((b << 9) + q) * 512 * 128);
        __syncthreads();

        for (int p = 0; (p << 5) + half < nk; ++p) {
            const int i = (((p << 4) + (w << 2) + rq) << 1) + half;
            if (i < nk) {
                const int k = kl_s[i];
                const float4* bp = brow + (size_t)k * 32;
                float4 v0 = bp[sg];
                float4 v1 = bp[16 + sg];

                float s  = v0.x+v0.y+v0.z+v0.w + v1.x+v1.y+v1.z+v1.w;
                float ss = v0.x*v0.x; ss = fmaf(v0.y,v0.y, ss); ss = fmaf(v0.z,v0.z, ss);
                ss = fmaf(v0.w,v0.w, ss); ss = fmaf(v1.x,v1.x, ss); ss = fmaf(v1.y,v1.y, ss);
                ss = fmaf(v1.z,v1.z, ss); ss = fmaf(v1.w,v1.w, ss);

                float4 dA = {0.f,0.f,0.f,0.f}, dB = {0.f,0.f,0.f,0.f};
                FMA4(dA, v0.x, cA0[0]); FMA4(dB, v0.x, cB0[0]);
                FMA4(dA, v0.y, cA0[1]); FMA4(dB, v0.y, cB0[1]);
                FMA4(dA, v0.z, cA0[2]); FMA4(dB, v0.z, cB0[2]);
                FMA4(dA, v0.w, cA0[3]); FMA4(dB, v0.w, cB0[3]);
                FMA4(dA, v1.x, cA1[0]); FMA4(dB, v1.x, cB1[0]);
                FMA4(dA, v1.y, cA1[1]); FMA4(dB, v1.y, cB1[1]);
                FMA4(dA, v1.z, cA1[2]); FMA4(dB, v1.z, cB1[2]);
                FMA4(dA, v1.w, cA1[3]); FMA4(dB, v1.w, cB1[3]);

                float dsum = hred16(dA, dB, sg);
                #pragma unroll
                for (int m = 1; m < 16; m <<= 1) {
                    s  += __shfl_xor(s,  m);
                    ss += __shfl_xor(ss, m);
                }
                float mean = s * (1.f/128.f);
                float rstd = rsqrtf(ss*(1.f/128.f) - mean*mean + 1e-5f);
                if (sg < 8)
                    bh[((size_t)((b*8 + h) * 512) + q) * 512 + k] = rstd * (dsum - mean*S1) + S2;
            }
        }
        return;
    }

    // ---------------- proj path: 4 rows + out-init ----------------
    const int gr0 = blockIdx.x * 4;
    const int row = gr0 + w;

    float4 xv = *reinterpret_cast<const float4*>(x + (size_t)row * 256 + lane * 4);
    float s  = xv.x + xv.y + xv.z + xv.w;
    float ss = xv.x*xv.x + xv.y*xv.y + xv.z*xv.z + xv.w*xv.w;
    #pragma unroll
    for (int m = 1; m < 64; m <<= 1) { s += __shfl_xor(s, m); ss += __shfl_xor(ss, m); }
    float mean = s * (1.f/256.f);
    float rstd = rsqrtf(ss*(1.f/256.f) - mean*mean + 1e-5f);
    float4 g4 = *reinterpret_cast<const float4*>(lng + lane*4);
    float4 b4 = *reinterpret_cast<const float4*>(lnb + lane*4);
    float4 xn;
    xn.x = (xv.x-mean)*rstd*g4.x + b4.x;
    xn.y = (xv.y-mean)*rstd*g4.y + b4.y;
    xn.z = (xv.z-mean)*rstd*g4.z + b4.z;
    xn.w = (xv.w-mean)*rstd*g4.w + b4.w;
    *reinterpret_cast<float4*>(&xn_s[w][lane*4]) = xn;

    // out init: bo for unmasked rows, 0 for masked (KB atomically adds head terms)
    float bov = bo[tid];
    #pragma unroll
    for (int r = 0; r < 4; ++r) {
        int gr = gr0 + r;
        out[(size_t)gr * 256 + tid] = (mask[gr] == 0) ? 0.f : bov;
    }
    __syncthreads();

    const float* W = (w == 0) ? Wq : (w == 1) ? Wk : (w == 2) ? Wv : Wg;
    const int col = lane << 2;
    float a[4][4];
    #pragma unroll
    for (int r = 0; r < 4; ++r)
        #pragma unroll
        for (int c = 0; c < 4; ++c) a[r][c] = 0.f;

    #pragma unroll 4
    for (int c = 0; c < 256; c += 4) {
        float4 w0 = *reinterpret_cast<const float4*>(W + (size_t)(c+0)*256 + col);
        float4 w1 = *reinterpret_cast<const float4*>(W + (size_t)(c+1)*256 + col);
        float4 w2 = *reinterpret_cast<const float4*>(W + (size_t)(c+2)*256 + col);
        float4 w3 = *reinterpret_cast<const float4*>(W + (size_t)(c+3)*256 + col);
        #pragma unroll
        for (int r = 0; r < 4; ++r) {
            float4 xr = *reinterpret_cast<const float4*>(&xn_s[r][c]);
            a[r][0] = fmaf(xr.x,w0.x, fmaf(xr.y,w1.x, fmaf(xr.z,w2.x, fmaf(xr.w,w3.x, a[r][0]))));
            a[r][1] = fmaf(xr.x,w0.y, fmaf(xr.y,w1.y, fmaf(xr.z,w2.y, fmaf(xr.w,w3.y, a[r][1]))));
            a[r][2] = fmaf(xr.x,w0.z, fmaf(xr.y,w1.z, fmaf(xr.z,w2.z, fmaf(xr.w,w3.z, a[r][2]))));
            a[r][3] = fmaf(xr.x,w0.w, fmaf(xr.y,w1.w, fmaf(xr.z,w2.w, fmaf(xr.w,w3.w, a[r][3]))));
        }
    }

    if (w == 0) {
        #pragma unroll
        for (int r = 0; r < 4; ++r) {
            float4 o; o.x=a[r][0]; o.y=a[r][1]; o.z=a[r][2]; o.w=a[r][3];
            *reinterpret_cast<float4*>(qg + (size_t)(gr0+r)*256 + col) = o;
        }
    } else if (w == 1) {
        #pragma unroll
        for (int r = 0; r < 4; ++r) {
            int gr = gr0 + r, gb = gr >> 9, gl = gr & 511;
            #pragma unroll
            for (int jj = 0; jj < 4; ++jj) {
                int c2 = col + jj;
                ktg[((size_t)(gb*8 + (c2>>5))*32 + (c2&31))*512 + gl] = a[r][jj] * QK_SCALE;
            }
        }
    } else if (w == 2) {
        #pragma unroll
        for (int r = 0; r < 4; ++r) {
            float4 o; o.x=a[r][0]; o.y=a[r][1]; o.z=a[r][2]; o.w=a[r][3];
            *reinterpret_cast<float4*>(vg + (size_t)(gr0+r)*256 + col) = o;
        }
    } else {
        float4 bg4 = *reinterpret_cast<const float4*>(bgv + col);
        #pragma unroll
        for (int r = 0; r < 4; ++r) {
            float4 o;
            o.x = 1.f/(1.f + __expf(-(a[r][0] + bg4.x)));
            o.y = 1.f/(1.f + __expf(-(a[r][1] + bg4.y)));
            o.z = 1.f/(1.f + __expf(-(a[r][2] + bg4.z)));
            o.w = 1.f/(1.f + __expf(-(a[r][3] + bg4.w)));
            *reinterpret_cast<float4*>(gateg + (size_t)(gr0+r)*256 + col) = o;
        }
    }
}

// ================= KB: attention per (b,h,32q) + fused Wo epilogue (atomicAdd) =========
__global__ __launch_bounds__(512, 2) void kB(
    const float* __restrict__ qg, const float* __restrict__ ktg,
    const float* __restrict__ vg, const float* __restrict__ gateg,
    const float* __restrict__ bh, const int* __restrict__ mask,
    const float* __restrict__ Wo, float* __restrict__ out)
{
    __shared__ float kv_s[8192];        // K [32][128] | V [128][32]; reused for Wo slice
    __shared__ float q_s[32][32];
    __shared__ float p_s[8][4][128];
    __shared__ float att_s[32][32];

    const int tid = threadIdx.x;
    const int bid = blockIdx.x;
    const int b  = bid >> 7;
    const int h  = (bid >> 4) & 7;
    const int qt = bid & 15;
    const int w = tid >> 6, lane = tid & 63;
    const int ql = lane >> 5, dd2 = lane & 31;
    const int mq = b << 9;
    const int q0 = qt << 5;
    const int qw = q0 + (w << 2);

    {
        int qr = tid >> 4, dd = (tid & 15) << 1;
        float2 v = *reinterpret_cast<const float2*>(
            qg + (size_t)(mq + q0 + qr) * 256 + (h << 5) + dd);
        *reinterpret_cast<float2*>(&q_s[qr][dd]) = v;
    }

    float mrun[4] = {-1e30f, -1e30f, -1e30f, -1e30f};
    float sden[4] = {0.f, 0.f, 0.f, 0.f};
    float a0A=0.f, a0B=0.f, a1A=0.f, a1B=0.f;

    for (int kt2 = 0; kt2 < 4; ++kt2) {
        const int k0 = kt2 << 7;
        __syncthreads();
        {
            int d = tid >> 4, kk = (tid & 15) << 3;
            const float* src = ktg + ((size_t)((b << 3) + h) * 32 + d) * 512 + k0 + kk;
            float4 a4 = *reinterpret_cast<const float4*>(src);
            float4 b4 = *reinterpret_cast<const float4*>(src + 4);
            *reinterpret_cast<float4*>(&kv_s[d * 128 + kk])     = a4;
            *reinterpret_cast<float4*>(&kv_s[d * 128 + kk + 4]) = b4;
            int k = tid >> 2, dd = (tid & 3) << 3;
            const float* vs = vg + (size_t)(mq + k0 + k) * 256 + (h << 5) + dd;
            float4 c4 = *reinterpret_cast<const float4*>(vs);
            float4 e4 = *reinterpret_cast<const float4*>(vs + 4);
            *reinterpret_cast<float4*>(&kv_s[4096 + k * 32 + dd])     = c4;
            *reinterpret_cast<float4*>(&kv_s[4096 + k * 32 + dd + 4]) = e4;
        }
        __syncthreads();

        const int mkA = (mask[mq + k0 + lane] == 0);
        const int mkB = (mask[mq + k0 + 64 + lane] == 0);

        float bhA[4], bhB[4];
        #pragma unroll
        for (int qq = 0; qq < 4; ++qq) {
            const float* r = bh + (((size_t)(b*8 + h) * 512) + qw + qq) * 512 + k0;
            bhA[qq] = r[lane];
            bhB[qq] = r[64 + lane];
        }

        float lA[4] = {0.f,0.f,0.f,0.f}, lB[4] = {0.f,0.f,0.f,0.f};
        #pragma unroll
        for (int d4 = 0; d4 < 32; d4 += 4) {
            float4 q4[4];
            #pragma unroll
            for (int qq = 0; qq < 4; ++qq)
                q4[qq] = *reinterpret_cast<const float4*>(&q_s[(w << 2) + qq][d4]);
            float kv0[4], kv1[4];
            #pragma unroll
            for (int j = 0; j < 4; ++j) {
                kv0[j] = kv_s[(d4 + j) * 128 + lane];
                kv1[j] = kv_s[(d4 + j) * 128 + 64 + lane];
            }
            #pragma unroll
            for (int qq = 0; qq < 4; ++qq) {
                lA[qq] = fmaf(q4[qq].x, kv0[0], lA[qq]);
                lA[qq] = fmaf(q4[qq].y, kv0[1], lA[qq]);
                lA[qq] = fmaf(q4[qq].z, kv0[2], lA[qq]);
                lA[qq] = fmaf(q4[qq].w, kv0[3], lA[qq]);
                lB[qq] = fmaf(q4[qq].x, kv1[0], lB[qq]);
                lB[qq] = fmaf(q4[qq].y, kv1[1], lB[qq]);
                lB[qq] = fmaf(q4[qq].z, kv1[2], lB[qq]);
                lB[qq] = fmaf(q4[qq].w, kv1[3], lB[qq]);
            }
        }

        float corr4[4];
        #pragma unroll
        for (int qq = 0; qq < 4; ++qq) {
            float la = mkA ? -1e30f : (lA[qq] + bhA[qq]);
            float lb = mkB ? -1e30f : (lB[qq] + bhB[qq]);
            float mx = fmaxf(la, lb);
            #pragma unroll
            for (int m = 1; m < 64; m <<= 1) mx = fmaxf(mx, __shfl_xor(mx, m));
            float mnew = fmaxf(mrun[qq], mx);
            float corr = __expf(mrun[qq] - mnew);
            float pa = mkA ? 0.f : __expf(la - mnew);
            float pb = mkB ? 0.f : __expf(lb - mnew);
            float ts = pa + pb;
            #pragma unroll
            for (int m = 1; m < 64; m <<= 1) ts += __shfl_xor(ts, m);
            sden[qq] = sden[qq] * corr + ts;
            mrun[qq] = mnew;
            corr4[qq] = corr;
            p_s[w][qq][lane]      = pa;
            p_s[w][qq][64 + lane] = pb;
        }

        float c0 = ql ? corr4[1] : corr4[0];
        float c1 = ql ? corr4[3] : corr4[2];
        a0A *= c0; a0B *= c0; a1A *= c1; a1B *= c1;
        const float* pr0 = p_s[w][ql];
        const float* pr1 = p_s[w][ql + 2];
        #pragma unroll 4
        for (int k = 0; k < 128; k += 8) {
            float4 p0a = *reinterpret_cast<const float4*>(pr0 + k);
            float4 p0b = *reinterpret_cast<const float4*>(pr0 + k + 4);
            float4 p1a = *reinterpret_cast<const float4*>(pr1 + k);
            float4 p1b = *reinterpret_cast<const float4*>(pr1 + k + 4);
            float v0 = kv_s[4096 + (k+0)*32 + dd2], v1 = kv_s[4096 + (k+1)*32 + dd2];
            float v2 = kv_s[4096 + (k+2)*32 + dd2], v3 = kv_s[4096 + (k+3)*32 + dd2];
            float v4 = kv_s[4096 + (k+4)*32 + dd2], v5 = kv_s[4096 + (k+5)*32 + dd2];
            float v6 = kv_s[4096 + (k+6)*32 + dd2], v7 = kv_s[4096 + (k+7)*32 + dd2];
            a0A = fmaf(p0a.x,v0, fmaf(p0a.y,v1, fmaf(p0a.z,v2, fmaf(p0a.w,v3, a0A))));
            a0B = fmaf(p0b.x,v4, fmaf(p0b.y,v5, fmaf(p0b.z,v6, fmaf(p0b.w,v7, a0B))));
            a1A = fmaf(p1a.x,v0, fmaf(p1a.y,v1, fmaf(p1a.z,v2, fmaf(p1a.w,v3, a1A))));
            a1B = fmaf(p1b.x,v4, fmaf(p1b.y,v5, fmaf(p1b.z,v6, fmaf(p1b.w,v7, a1B))));
        }
    }

    // ---- gated, normalized head output -> LDS (masked q rows -> 0, guards NaN) ----
    {
        float sd0 = ql ? sden[1] : sden[0];
        float sd1 = ql ? sden[3] : sden[2];
        float g0 = gateg[(size_t)(mq + qw + ql) * 256 + (h << 5) + dd2];
        float g1 = gateg[(size_t)(mq + qw + ql + 2) * 256 + (h << 5) + dd2];
        int iv0 = (mask[mq + qw + ql] == 0);
        int iv1 = (mask[mq + qw + ql + 2] == 0);
        att_s[(w << 2) + ql][dd2]     = iv0 ? 0.f : (a0A + a0B) / sd0 * g0;
        att_s[(w << 2) + ql + 2][dd2] = iv1 ? 0.f : (a1A + a1B) / sd1 * g1;
    }
    __syncthreads();

    // ---- stage Wo head-slice [32][256] into kv_s (K/V space now free) ----
    {
        const float* wsrc = Wo + (size_t)h * 32 * 256;
        for (int i = tid; i < 2048; i += 512)
            *reinterpret_cast<float4*>(&kv_s[i << 2]) =
                *reinterpret_cast<const float4*>(wsrc + (i << 2));
    }
    __syncthreads();

    // ---- per-head partial of att @ Wo, atomically accumulated into out ----
    {
        const int c2 = tid & 255, qh = tid >> 8;   // qh in {0,1}: rows qh*16..+15
        float acc[16];
        #pragma unroll
        for (int i = 0; i < 16; ++i) acc[i] = 0.f;
        #pragma unroll
        for (int d4 = 0; d4 < 32; d4 += 4) {
            float w0 = kv_s[(d4+0)*256 + c2];
            float w1 = kv_s[(d4+1)*256 + c2];
            float w2 = kv_s[(d4+2)*256 + c2];
            float w3 = kv_s[(d4+3)*256 + c2];
            #pragma unroll
            for (int i = 0; i < 16; ++i) {
                float4 a4 = *reinterpret_cast<const float4*>(&att_s[(qh << 4) + i][d4]);
                acc[i] = fmaf(a4.x,w0, fmaf(a4.y,w1, fmaf(a4.z,w2, fmaf(a4.w,w3, acc[i]))));
            }
        }
        #pragma unroll
        for (int i = 0; i < 16; ++i)
            atomicAdd(out + (size_t)(mq + q0 + (qh << 4) + i) * 256 + c2, acc[i]);
    }
}

extern "C" void kernel_launch(void* const* d_in, const int* in_sizes, int n_in,
                              void* d_out, int out_size, void* d_ws, size_t ws_size,
                              hipStream_t stream)
{
    const float* x    = (const float*)d_in[0];
    const float* bias = (const float*)d_in[1];
    const int*   mask = (const int*)d_in[2];
    const float* lng  = (const float*)d_in[3];
    const float* lnb  = (const float*)d_in[4];
    const float* lnbg = (const float*)d_in[5];
    const float* lnbb = (const float*)d_in[6];
    const float* Wq   = (const float*)d_in[7];
    const float* Wk   = (const float*)d_in[8];
    const float* Wv   = (const float*)d_in[9];
    const float* Wb   = (const float*)d_in[10];
    const float* Wg   = (const float*)d_in[11];
    const float* bgv  = (const float*)d_in[12];
    const float* Wo   = (const float*)d_in[13];
    const float* bo   = (const float*)d_in[14];
    float* out = (float*)d_out;

    float* ws    = (float*)d_ws;
    float* qg    = ws;                    // 262144
    float* ktg   = qg    + 262144;        // 262144 [b][h][d][512]
    float* vg    = ktg   + 262144;        // 262144
    float* gateg = vg    + 262144;        // 262144
    float* bhg   = gateg + 262144;        // 4194304 [b][h][q][k]

    hipLaunchKernelGGL(kA, dim3(2304), dim3(256), 0, stream,
        x, mask, lng, lnb, Wq, Wk, Wv, Wg, bgv, lnbg, lnbb, Wb, bias, bo,
        qg, ktg, vg, gateg, bhg, out);
    hipLaunchKernelGGL(kB, dim3(256), dim3(512), 0, stream,
        qg, ktg, vg, gateg, bhg, mask, Wo, out);
}